// Round 16
// baseline (1376.907 us; speedup 1.0000x reference)
//
#include <hip/hip_runtime.h>
#include <cmath>

#define D_MODEL 1024
#define N_HEADS 16
#define HEAD_DIM 64
#define SEQ 1024
#define BATCH 4
#define FF_DIM 4096
#define IN_DIM 256
#define N_LAYERS 6
#define N_CLS 10

typedef __bf16 bf16x8 __attribute__((ext_vector_type(8)));
typedef __bf16 bf16x4 __attribute__((ext_vector_type(4)));
typedef float f32x4 __attribute__((ext_vector_type(4)));
typedef unsigned short u16x8 __attribute__((ext_vector_type(8)));

__device__ __forceinline__ unsigned short f2bf(float f) {
    return __builtin_bit_cast(unsigned short, (__bf16)f);   // RNE
}
__device__ __forceinline__ float bf2f(unsigned short u) {
    return __uint_as_float((unsigned int)u << 16);
}
__device__ __forceinline__ float fexp2(float x) {
    return __builtin_amdgcn_exp2f(x);   // v_exp_f32 (base-2 native)
}

__device__ __forceinline__ void gll16(const void* g, void* l) {
    __builtin_amdgcn_global_load_lds((const __attribute__((address_space(1))) void*)g,
                                     (__attribute__((address_space(3))) void*)l, 16, 0, 0);
}

// ---------------------------------------------------------------------------
// f32 -> bf16 convert (vectorized) — only used for the input activations x.
// ---------------------------------------------------------------------------
__global__ __launch_bounds__(256)
void cvt_f32_bf16(const float* __restrict__ src, unsigned short* __restrict__ dst, int n) {
    int i = (blockIdx.x * 256 + threadIdx.x) * 4;
    if (i + 4 <= n) {
        float4 v = *(const float4*)(src + i);
        ushort4 o;
        o.x = f2bf(v.x); o.y = f2bf(v.y); o.z = f2bf(v.z); o.w = f2bf(v.w);
        *(ushort4*)(dst + i) = o;
    }
}

// ---------------------------------------------------------------------------
// 256x256 NT GEMM, A bf16 [M][lda], B **f32** [N][lda] (weights direct, no
// pre-conversion pass). Corrected memory plan (round-15 had A slabs half-
// sized and a 192KB total): A double-buffered 4 x 16KB kh-slabs (64KB) +
// B f32 3-slab RING 3 x 32KB (96KB) = 160KB exactly.
// Per-tile 4-phase loop (mu x kh): ring r0=(2t)%3 holds (t,kh0), r1=(2t+1)%3
// holds (t,kh1), r2=(2t+2)%3 receives (t+1,kh0). Stages: B(r2,kh0,t+1)@ph1,
// A(b^1,0,t+1)@ph2, B(r0,kh1,t+1)@ph3 [r0 free: B frags reused from regs
// after ph1], A(b^1,1,t+1)@ph4. Gates vmcnt(6) at ph2/ph4 (=one phase-pair
// B4+A2 in flight), vmcnt(0) at tail. B converted bf16 at fragment-read
// (RNE — bit-identical to the old cvt_layer path).
// ---------------------------------------------------------------------------
template<int MU, bool LOADB, bool GATE, typename F>
__device__ __forceinline__
void gphase(f32x4 (&acc)[8][4], bf16x8 (&bfr)[4],
            const unsigned short* slabA, const float* slabB,
            const int (&aoff)[2][4], const int (&boffB)[4][2], F&& stage, bool gate0)
{
    bf16x8 afr[4];
    if (LOADB) {
        _Pragma("unroll")
        for (int n = 0; n < 4; ++n) {
            f32x4 lo = *(const f32x4*)(slabB + boffB[n][0]);
            f32x4 hi = *(const f32x4*)(slabB + boffB[n][1]);
            bf16x8 r;
            _Pragma("unroll")
            for (int j = 0; j < 4; ++j) { r[j] = (__bf16)lo[j]; r[4 + j] = (__bf16)hi[j]; }
            bfr[n] = r;
        }
    }
    _Pragma("unroll")
    for (int m = 0; m < 4; ++m) afr[m] = *(const bf16x8*)(slabA + aoff[MU][m]);
    stage();
    __builtin_amdgcn_s_barrier();
    asm volatile("s_waitcnt lgkmcnt(0)" ::: "memory");
    __builtin_amdgcn_sched_barrier(0);
    __builtin_amdgcn_s_setprio(1);
    _Pragma("unroll")
    for (int m = 0; m < 4; ++m)
        _Pragma("unroll")
        for (int n = 0; n < 4; ++n)
            acc[MU * 4 + m][n] =
                __builtin_amdgcn_mfma_f32_16x16x32_bf16(afr[m], bfr[n], acc[MU * 4 + m][n], 0, 0, 0);
    __builtin_amdgcn_s_setprio(0);
    if (GATE) {
        if (gate0) asm volatile("s_waitcnt vmcnt(0)" ::: "memory");
        else       asm volatile("s_waitcnt vmcnt(6)" ::: "memory");
    }
    __builtin_amdgcn_s_barrier();
}

__global__ __launch_bounds__(512, 1)
void gemm256(const unsigned short* __restrict__ A, const float* __restrict__ B,
             const float* __restrict__ bias,
             float* __restrict__ Cf, unsigned short* __restrict__ Cb,
             int N, int lda, int klen, int relu, size_t slab_stride)
{
    extern __shared__ unsigned short lds[];   // 163840 B: A 4x16KB | B-ring 3x32KB
    auto slA  = [&](int buf, int kh) { return lds + (buf * 2 + kh) * 8192; };
    auto slBr = [&](int ring) { return (float*)(lds + 32768 + ring * 16384); };

    const int nbc = N >> 8;
    const int nwg = gridDim.x;
    const int orig = blockIdx.x;
    const int xcd = orig & 7, lid = orig >> 3;
    const int q = nwg >> 3, r = nwg & 7;
    const int wgid = (xcd < r ? xcd * (q + 1) : r * (q + 1) + (xcd - r) * q) + lid;
    const int brow = wgid / nbc, bcol = wgid % nbc;
    const int kpart = blockIdx.y;

    const int tid = threadIdx.x;
    const int w = tid >> 6, l = tid & 63;
    const int wr = w >> 2, wc = w & 3;
    const int lr = l & 15, lg4 = l >> 4;

    const unsigned short* Ab = A + (size_t)brow * 256 * lda + (size_t)kpart * klen;
    const float*          Bb = B + (size_t)bcol * 256 * lda + (size_t)kpart * klen;
    float* Cfp = Cf;
    unsigned short* Cbp = Cb ? Cb + (size_t)kpart * slab_stride : nullptr;
    const float* biasp = (kpart == 0) ? bias : nullptr;

    // --- A staging: granules G0 (row tr0) and G0+64 (row tr0+16), 16KB slab
    const int G0 = w * 128 + l;
    const int tr0 = G0 >> 2;
    const int lg0 = (G0 & 3) ^ ((tr0 >> 1) & 3);

    auto stA = [&](int buf, int kh, int tile) {
        unsigned short* d = slA(buf, kh) + G0 * 8;
        const unsigned short* s = Ab + (size_t)tr0 * lda + tile * 64 + kh * 32 + lg0 * 8;
        gll16(s, d);
        gll16(s + (size_t)16 * lda, d + 512);
    };
    // --- B staging (f32): 2048 granules of 4 f32; thread covers tid + c*512.
    // dest linear per wave; source k-granule = gq ^ (row&7) (involution).
    auto stB = [&](int ring, int kh, int tile) {
        float* dst = slBr(ring);
        const float* sb = Bb + tile * 64 + kh * 32;
        #pragma unroll
        for (int c = 0; c < 4; ++c) {
            int G = tid + c * 512;
            int row = G >> 3, gq = G & 7;
            int ksrc = gq ^ (row & 7);
            gll16(sb + (size_t)row * lda + ksrc * 4, dst + G * 4);
        }
    };

    int aoff[2][4], boffB[4][2];
    #pragma unroll
    for (int mu = 0; mu < 2; ++mu)
        #pragma unroll
        for (int m = 0; m < 4; ++m) {
            int tA = wr * 128 + mu * 64 + m * 16 + lr;
            aoff[mu][m] = tA * 32 + ((lg4 ^ ((tA >> 1) & 3)) << 3);
        }
    #pragma unroll
    for (int n = 0; n < 4; ++n) {
        int tB = wc * 64 + n * 16 + lr;
        #pragma unroll
        for (int c = 0; c < 2; ++c)
            boffB[n][c] = tB * 32 + (((2 * lg4 + c) ^ (tB & 7)) << 2);
    }

    f32x4 acc[8][4] = {};

    const int KT = klen >> 6;
    // prologue: tile 0 -> A(0,*), B ring slabs 0 (kh0) and 1 (kh1); drain.
    stA(0, 0, 0); stA(0, 1, 0);
    stB(0, 0, 0); stB(1, 1, 0);
    asm volatile("s_waitcnt vmcnt(0)" ::: "memory");
    __builtin_amdgcn_s_barrier();

    for (int t = 0; t < KT; ++t) {
        const int b = t & 1;
        const bool more = (t + 1 < KT);
        const int r0 = (2 * t) % 3, r1 = (2 * t + 1) % 3, r2 = (2 * t + 2) % 3;
        bf16x8 bfr[4];
        gphase<0, true , false>(acc, bfr, slA(b, 0), slBr(r0), aoff, boffB,
                                [&]{ if (more) stB(r2, 0, t + 1); }, false);
        gphase<1, false, true >(acc, bfr, slA(b, 0), slBr(r0), aoff, boffB,
                                [&]{ if (more) stA(b ^ 1, 0, t + 1); }, !more);
        gphase<0, true , false>(acc, bfr, slA(b, 1), slBr(r1), aoff, boffB,
                                [&]{ if (more) stB(r0, 1, t + 1); }, false);
        gphase<1, false, true >(acc, bfr, slA(b, 1), slBr(r1), aoff, boffB,
                                [&]{ if (more) stA(b ^ 1, 1, t + 1); }, !more);
    }

    const int crow0 = brow * 256 + wr * 128;
    const int ccol0 = bcol * 256 + wc * 64;
    #pragma unroll
    for (int n = 0; n < 4; ++n) {
        int col = ccol0 + n * 16 + lr;
        float bv = biasp ? biasp[col] : 0.0f;
        #pragma unroll
        for (int m = 0; m < 8; ++m) {
            int row0 = crow0 + m * 16 + lg4 * 4;
            size_t base_i = (size_t)row0 * N + col;
            #pragma unroll
            for (int j = 0; j < 4; ++j) {
                float v = acc[m][n][j] + bv;
                if (relu) v = fmaxf(v, 0.0f);
                size_t idx = base_i + (size_t)j * N;
                if (Cfp) Cfp[idx] = v;
                if (Cbp) Cbp[idx] = f2bf(v);
            }
        }
    }
}

// ---------------------------------------------------------------------------
// Flash attention, scalar-slope ALiBi. QBLK=64, two k-tiles per iteration,
// T5 setprio, min-3-waves/EU, BAND TRUNCATION over {qt-2..qt+2}
// (error below bf16 ulp — see round-13 analysis).
// ---------------------------------------------------------------------------
__global__ __launch_bounds__(256, 3)
void attn_alibi(const unsigned short* __restrict__ qkv,
                unsigned short* __restrict__ out,
                float slope2)   // slope * log2(e)
{
    const int bid = blockIdx.x;
    const int id = (bid & 7) * 128 + (bid >> 3);   // XCD-chunk: one (b,h) per L2
    const int qt = id & 15;
    const int bh = id >> 4;
    const int h  = bh & (N_HEADS - 1);
    const int b  = bh >> 4;
    const int w  = threadIdx.x >> 6, l = threadIdx.x & 63;
    const int lr = l & 15, lg = l >> 4;

    __shared__ __align__(16) unsigned short lsK[2][64 * 64];
    __shared__ __align__(16) unsigned short lsVt[2][64 * 64];
    __shared__ __align__(16) unsigned short lsP[4 * 16 * 64];

    const size_t rs = 3 * D_MODEL;
    const unsigned short* base = qkv + (size_t)b * SEQ * rs;
    const int qrow_w = qt * 64 + w * 16;
    const float c1 = 0.125f * 1.4426950408889634f;   // scale * log2(e)

    bf16x8 aq[2];
    #pragma unroll
    for (int ks = 0; ks < 2; ++ks)
        aq[ks] = *(const bf16x8*)(base + (size_t)(qrow_w + lr) * rs + h * HEAD_DIM + ks * 32 + lg * 8);

    float m_run = -1e30f, s_run = 0.f;
    f32x4 oacc[4] = {};
    const float qi = (float)(qrow_w + lr);   // this lane's q row (for S^T)

    auto stageK = [&](int buf, int kt) {
        #pragma unroll
        for (int i = 0; i < 2; ++i) {
            int chunk = i * 4 + w;
            int e = chunk * 512 + l * 8;
            int row = e >> 6, c = e & 63;
            int gcol = c ^ ((row & 7) << 3);
            gll16(base + (size_t)(kt * 64 + row) * rs + D_MODEL + h * HEAD_DIM + gcol,
                  &lsK[buf][chunk * 512]);
        }
    };
    auto stageV = [&](int buf, int kt) {
        #pragma unroll
        for (int i = 0; i < 2; ++i) {
            int oct = i * 4 + w;
            int kj  = l;
            u16x8 v = *(const u16x8*)(base + (size_t)(kt * 64 + kj) * rs + 2 * D_MODEL + h * HEAD_DIM + oct * 8);
            #pragma unroll
            for (int jj = 0; jj < 8; ++jj) {
                int row = oct * 8 + jj;
                lsVt[buf][row * 64 + (kj ^ ((row & 7) << 3))] = v[jj];
            }
        }
    };

    // band: pairs p covering k-tiles {qt-2..qt+2} (clamped)
    const int p_lo = max(0, (qt - 2) >> 1);
    const int p_hi = min(SEQ / 128, ((qt + 2) >> 1) + 1);

    for (int p = p_lo; p < p_hi; ++p) {
        const int kt0 = 2 * p;
        stageK(0, kt0); stageK(1, kt0 + 1);
        stageV(0, kt0); stageV(1, kt0 + 1);
        __syncthreads();

        // --- QK^T swapped, both tiles (independent MFMA chains)
        f32x4 s0[4] = {}, s1[4] = {};
        __builtin_amdgcn_s_setprio(1);
        #pragma unroll
        for (int ks = 0; ks < 2; ++ks) {
            #pragma unroll
            for (int n = 0; n < 4; ++n) {
                int row = n * 16 + lr;
                int co = (ks * 32 + lg * 8) ^ ((row & 7) << 3);
                bf16x8 bk0 = *(const bf16x8*)&lsK[0][row * 64 + co];
                bf16x8 bk1 = *(const bf16x8*)&lsK[1][row * 64 + co];
                s0[n] = __builtin_amdgcn_mfma_f32_16x16x32_bf16(bk0, aq[ks], s0[n], 0, 0, 0);
                s1[n] = __builtin_amdgcn_mfma_f32_16x16x32_bf16(bk1, aq[ks], s1[n], 0, 0, 0);
            }
        }
        __builtin_amdgcn_s_setprio(0);

        // --- joint ALiBi + max over both tiles (32 scores/lane)
        float mx = -1e30f;
        #pragma unroll
        for (int n = 0; n < 4; ++n)
            #pragma unroll
            for (int jj = 0; jj < 4; ++jj) {
                float k0f = (float)(kt0 * 64 + n * 16 + lg * 4 + jj);
                float v0 = fmaf(s0[n][jj], c1, -slope2 * fabsf(qi - k0f));
                float v1 = fmaf(s1[n][jj], c1, -slope2 * fabsf(qi - k0f - 64.0f));
                s0[n][jj] = v0;
                s1[n][jj] = v1;
                mx = fmaxf(mx, fmaxf(v0, v1));
            }
        mx = fmaxf(mx, __shfl_xor(mx, 16));
        mx = fmaxf(mx, __shfl_xor(mx, 32));
        if (__any(mx > m_run + 8.0f)) {
            float mnew = fmaxf(m_run, mx);
            float corr = fexp2(m_run - mnew);
            m_run = mnew;
            s_run *= corr;
            #pragma unroll
            for (int j = 0; j < 4; ++j) {
                float cj = __shfl(corr, lg * 4 + j);   // corr g-uniform: lane q=lg*4+j
                #pragma unroll
                for (int nd = 0; nd < 4; ++nd)
                    oacc[nd][j] *= cj;
            }
        }
        // --- exp both tiles, interleaved (independent chains)
        float psum = 0.f;
        #pragma unroll
        for (int n = 0; n < 4; ++n)
            #pragma unroll
            for (int jj = 0; jj < 4; ++jj) {
                float p0 = fexp2(s0[n][jj] - m_run);
                float p1 = fexp2(s1[n][jj] - m_run);
                s0[n][jj] = p0;
                s1[n][jj] = p1;
                psum += p0 + p1;
            }
        psum += __shfl_xor(psum, 16);
        psum += __shfl_xor(psum, 32);
        s_run += psum;

        // --- pack P + PV, tile 0 then tile 1 (wave-local lsP region)
        #pragma unroll
        for (int t = 0; t < 2; ++t) {
            #pragma unroll
            for (int n = 0; n < 4; ++n) {
                f32x4 sv = t ? s1[n] : s0[n];
                bf16x4 pk;
                pk[0] = (__bf16)sv[0]; pk[1] = (__bf16)sv[1];
                pk[2] = (__bf16)sv[2]; pk[3] = (__bf16)sv[3];
                *(bf16x4*)&lsP[w * 1024 + lr * 64 + ((n * 16 + lg * 4) ^ ((lr & 7) << 3))] = pk;
            }
            __builtin_amdgcn_s_setprio(1);
            #pragma unroll
            for (int ks = 0; ks < 2; ++ks) {
                bf16x8 ap = *(const bf16x8*)&lsP[w * 1024 + lr * 64 + ((ks * 32 + lg * 8) ^ ((lr & 7) << 3))];
                #pragma unroll
                for (int nd = 0; nd < 4; ++nd) {
                    int row = nd * 16 + lr;
                    bf16x8 bv = *(const bf16x8*)&lsVt[t][row * 64 + ((ks * 32 + lg * 8) ^ ((row & 7) << 3))];
                    oacc[nd] = __builtin_amdgcn_mfma_f32_16x16x32_bf16(ap, bv, oacc[nd], 0, 0, 0);
                }
            }
            __builtin_amdgcn_s_setprio(0);
        }
        __syncthreads();
    }

    // --- normalize (1/s_run lives at lane q=lr; broadcast to oacc layout)
    float inv = 1.0f / s_run;
    #pragma unroll
    for (int j = 0; j < 4; ++j) {
        float invj = __shfl(inv, lg * 4 + j);
        int qrow = qrow_w + lg * 4 + j;
        #pragma unroll
        for (int nd = 0; nd < 4; ++nd) {
            int d = nd * 16 + lr;
            out[((size_t)b * SEQ + qrow) * D_MODEL + h * HEAD_DIM + d] = f2bf(oacc[nd][j] * invj);
        }
    }
}

// ---------------------------------------------------------------------------
// Wave-level add+LN: 1 row per WAVE (4 rows/block, grid MT/4). Lane owns 16
// elems as two perfect 16B bursts; reduction = 6 shfl_xor, no LDS/barrier.
// ---------------------------------------------------------------------------
__global__ __launch_bounds__(256)
void add_ln(const unsigned short* __restrict__ resid, const unsigned short* __restrict__ delta,
            size_t slab, int nslab,
            const float* __restrict__ g, const float* __restrict__ beta,
            unsigned short* __restrict__ out_b)
{
    const int w = threadIdx.x >> 6, l = threadIdx.x & 63;
    const int row = blockIdx.x * 4 + w;
    const size_t off0 = (size_t)row * D_MODEL + l * 8;

    float x[16];
    #pragma unroll
    for (int c = 0; c < 2; ++c) {
        u16x8 rv = *(const u16x8*)(resid + off0 + c * 512);
        #pragma unroll
        for (int j = 0; j < 8; ++j) x[c * 8 + j] = bf2f(rv[j]);
    }
    for (int p = 0; p < nslab; ++p) {
        #pragma unroll
        for (int c = 0; c < 2; ++c) {
            u16x8 dv = *(const u16x8*)(delta + p * slab + off0 + c * 512);
            #pragma unroll
            for (int j = 0; j < 8; ++j) x[c * 8 + j] += bf2f(dv[j]);
        }
    }
    float s = 0.f, s2 = 0.f;
    #pragma unroll
    for (int i = 0; i < 16; ++i) { s += x[i]; s2 += x[i] * x[i]; }
    #pragma unroll
    for (int d = 1; d < 64; d <<= 1) {
        s  += __shfl_xor(s, d);
        s2 += __shfl_xor(s2, d);
    }
    float mu  = s * (1.0f / D_MODEL);
    float var = s2 * (1.0f / D_MODEL) - mu * mu;
    float rsq = rsqrtf(var + 1e-5f);

    #pragma unroll
    for (int c = 0; c < 2; ++c) {
        int e0 = l * 8 + c * 512;
        float4 g0 = *(const float4*)(g + e0);
        float4 g1 = *(const float4*)(g + e0 + 4);
        float4 b0 = *(const float4*)(beta + e0);
        float4 b1 = *(const float4*)(beta + e0 + 4);
        float gv[8] = {g0.x, g0.y, g0.z, g0.w, g1.x, g1.y, g1.z, g1.w};
        float bv[8] = {b0.x, b0.y, b0.z, b0.w, b1.x, b1.y, b1.z, b1.w};
        u16x8 ov;
        #pragma unroll
        for (int j = 0; j < 8; ++j)
            ov[j] = f2bf((x[c * 8 + j] - mu) * rsq * gv[j] + bv[j]);
        *(u16x8*)(out_b + off0 + c * 512) = ov;
    }
}

// ---------------------------------------------------------------------------
// Head: grid = N_CLS blocks x 256 threads; wave wv handles (b=wv, c=blockIdx).
// ---------------------------------------------------------------------------
__global__ __launch_bounds__(256)
void head_kernel(const unsigned short* __restrict__ h, const float* __restrict__ hw,
                 const float* __restrict__ hb, float* __restrict__ out)
{
    const int wv = threadIdx.x >> 6, l = threadIdx.x & 63;
    const int c = blockIdx.x;
    const unsigned short* hr = h + ((size_t)wv * SEQ + (SEQ - 1)) * D_MODEL;
    const float* wc = hw + (size_t)c * D_MODEL;
    float s = 0.f;
    #pragma unroll
    for (int i = 0; i < 16; ++i) {
        int k = i * 64 + l;
        s += bf2f(hr[k]) * wc[k];
    }
    #pragma unroll
    for (int d = 1; d < 64; d <<= 1)
        s += __shfl_xor(s, d);
    if (l == 0) out[wv * N_CLS + c] = s + hb[c];
}

// ---------------------------------------------------------------------------
extern "C" void kernel_launch(void* const* d_in, const int* in_sizes, int n_in,
                              void* d_out, int out_size, void* d_ws, size_t ws_size,
                              hipStream_t stream)
{
    const float* x     = (const float*)d_in[0];
    const float* in_w  = (const float*)d_in[1];
    const float* in_b  = (const float*)d_in[2];
    const float* Wqkv  = (const float*)d_in[3];
    const float* bqkv  = (const float*)d_in[4];
    const float* Wo    = (const float*)d_in[5];
    const float* bo    = (const float*)d_in[6];
    const float* ln1g  = (const float*)d_in[7];
    const float* ln1b  = (const float*)d_in[8];
    const float* ln2g  = (const float*)d_in[9];
    const float* ln2b  = (const float*)d_in[10];
    const float* W1    = (const float*)d_in[11];
    const float* b1    = (const float*)d_in[12];
    const float* W2    = (const float*)d_in[13];
    const float* b2    = (const float*)d_in[14];
    const float* headw = (const float*)d_in[15];
    const float* headb = (const float*)d_in[16];
    float* out = (float*)d_out;

    (void)hipFuncSetAttribute((const void*)gemm256, hipFuncAttributeMaxDynamicSharedMemorySize, 163840);

    char* ws = (char*)d_ws;
    size_t off = 0;
    auto alloc = [&](size_t bytes) -> void* {
        void* p = ws + off;
        off += (bytes + 255) & ~(size_t)255;
        return p;
    };
    const int MT = BATCH * SEQ;  // 4096
    const size_t SLAB = (size_t)MT * D_MODEL;
    const int WQKV_SZ = 3 * D_MODEL * D_MODEL;
    const int WO_SZ   = D_MODEL * D_MODEL;
    const int W1_SZ   = FF_DIM * D_MODEL;
    const int W2_SZ   = D_MODEL * FF_DIM;

    unsigned short* x_bf   = (unsigned short*)alloc((size_t)MT * IN_DIM * 2);
    unsigned short* h_bf   = (unsigned short*)alloc(SLAB * 2);
    unsigned short* qkv_bf = (unsigned short*)alloc((size_t)MT * 3 * D_MODEL * 2);
    unsigned short* att_bf = (unsigned short*)alloc(SLAB * 2);
    unsigned short* ff_bf  = (unsigned short*)alloc((size_t)MT * FF_DIM * 2);
    unsigned short* tmp_bf = (unsigned short*)alloc(SLAB * 2 * 4);   // up to 4 bf16 split-K slabs

    double ssum = 0.0;
    for (int i = 1; i <= N_HEADS; ++i) ssum += pow(2.0, -8.0 * i / N_HEADS);
    const float slope = (float)(ssum / N_HEADS);
    const float slope2 = slope * 1.4426950408889634f;

    // input projection: M=4096, N=1024, K=256 (bf16 A; f32 weights direct)
    cvt_f32_bf16<<<(MT * IN_DIM) / 1024, 256, 0, stream>>>(x, x_bf, MT * IN_DIM);
    gemm256<<<dim3(16 * 4, 1), 512, 163840, stream>>>(
        x_bf, in_w, in_b, nullptr, h_bf, D_MODEL, IN_DIM, IN_DIM, 0, 0);

    for (int layer = 0; layer < N_LAYERS; ++layer) {
        // QKV: M=4096, N=3072, K=1024 -> 192 blocks
        gemm256<<<dim3(16 * 12, 1), 512, 163840, stream>>>(
            h_bf, Wqkv + (size_t)layer * WQKV_SZ, bqkv + (size_t)layer * 3 * D_MODEL,
            nullptr, qkv_bf, 3 * D_MODEL, D_MODEL, D_MODEL, 0, 0);

        attn_alibi<<<BATCH * N_HEADS * (SEQ / 64), 256, 0, stream>>>(qkv_bf, att_bf, slope2);

        // Wo: split-K x2 -> 128 blocks, bf16 partials
        gemm256<<<dim3(16 * 4, 2), 512, 163840, stream>>>(
            att_bf, Wo + (size_t)layer * WO_SZ, bo + (size_t)layer * D_MODEL,
            nullptr, tmp_bf, D_MODEL, D_MODEL, D_MODEL / 2, 0, SLAB);

        add_ln<<<MT / 4, 256, 0, stream>>>(h_bf, tmp_bf, SLAB, 2,
            ln1g + (size_t)layer * D_MODEL, ln1b + (size_t)layer * D_MODEL, h_bf);

        // FF1: M=4096, N=4096, K=1024 -> 256 blocks, ReLU
        gemm256<<<dim3(16 * 16, 1), 512, 163840, stream>>>(
            h_bf, W1 + (size_t)layer * W1_SZ, b1 + (size_t)layer * FF_DIM,
            nullptr, ff_bf, FF_DIM, D_MODEL, D_MODEL, 1, 0);

        // FF2: split-K x4 -> 256 blocks, bf16 partials
        gemm256<<<dim3(16 * 4, 4), 512, 163840, stream>>>(
            ff_bf, W2 + (size_t)layer * W2_SZ, b2 + (size_t)layer * D_MODEL,
            nullptr, tmp_bf, D_MODEL, FF_DIM, FF_DIM / 4, 0, SLAB);

        add_ln<<<MT / 4, 256, 0, stream>>>(h_bf, tmp_bf, SLAB, 4,
            ln2g + (size_t)layer * D_MODEL, ln2b + (size_t)layer * D_MODEL, h_bf);
    }

    head_kernel<<<N_CLS, 256, 0, stream>>>(h_bf, headw, headb, out);
}

// Round 17
// 1234.210 us; speedup vs baseline: 1.1156x; 1.1156x over previous
//
#include <hip/hip_runtime.h>
#include <cmath>

#define D_MODEL 1024
#define N_HEADS 16
#define HEAD_DIM 64
#define SEQ 1024
#define BATCH 4
#define FF_DIM 4096
#define IN_DIM 256
#define N_LAYERS 6
#define N_CLS 10

typedef __bf16 bf16x8 __attribute__((ext_vector_type(8)));
typedef __bf16 bf16x4 __attribute__((ext_vector_type(4)));
typedef float f32x4 __attribute__((ext_vector_type(4)));
typedef unsigned short u16x8 __attribute__((ext_vector_type(8)));

__device__ __forceinline__ unsigned short f2bf(float f) {
    return __builtin_bit_cast(unsigned short, (__bf16)f);   // RNE; pairs fuse to v_cvt_pk_bf16_f32
}
__device__ __forceinline__ float bf2f(unsigned short u) {
    return __uint_as_float((unsigned int)u << 16);
}
__device__ __forceinline__ float fexp2(float x) {
    return __builtin_amdgcn_exp2f(x);   // v_exp_f32 (base-2 native)
}

__device__ __forceinline__ void gll16(const void* g, void* l) {
    __builtin_amdgcn_global_load_lds((const __attribute__((address_space(1))) void*)g,
                                     (__attribute__((address_space(3))) void*)l, 16, 0, 0);
}

// ---------------------------------------------------------------------------
// f32 -> bf16 convert (vectorized)
// ---------------------------------------------------------------------------
__global__ __launch_bounds__(256)
void cvt_f32_bf16(const float* __restrict__ src, unsigned short* __restrict__ dst, int n) {
    int i = (blockIdx.x * 256 + threadIdx.x) * 4;
    if (i + 4 <= n) {
        float4 v = *(const float4*)(src + i);
        ushort4 o;
        o.x = f2bf(v.x); o.y = f2bf(v.y); o.z = f2bf(v.z); o.w = f2bf(v.w);
        *(ushort4*)(dst + i) = o;
    }
}

// ---------------------------------------------------------------------------
// One-shot per-layer weight convert: Wqkv | Wo | W1 | W2 in a single launch.
// (Round-16 lesson: this bf16 pre-pass HALVES the GEMM working set — keeping
// it beats staging f32 weights directly: 84 µs pre-pass vs +230 µs in-loop.)
// ---------------------------------------------------------------------------
#define WQKV_SZ (3 * D_MODEL * D_MODEL)
#define WO_SZ   (D_MODEL * D_MODEL)
#define W1_SZ   (FF_DIM * D_MODEL)
#define W2_SZ   (D_MODEL * FF_DIM)
__global__ __launch_bounds__(256)
void cvt_layer(const float* __restrict__ wq, const float* __restrict__ wo,
               const float* __restrict__ w1, const float* __restrict__ w2,
               unsigned short* __restrict__ dq, unsigned short* __restrict__ dvo,
               unsigned short* __restrict__ d1, unsigned short* __restrict__ d2)
{
    int i = (blockIdx.x * 256 + threadIdx.x) * 4;
    const float* s; unsigned short* d; int off;
    if (i < WQKV_SZ)                    { s = wq; d = dq;  off = i; }
    else if (i < WQKV_SZ + WO_SZ)       { s = wo; d = dvo; off = i - WQKV_SZ; }
    else if (i < WQKV_SZ + WO_SZ + W1_SZ) { s = w1; d = d1; off = i - WQKV_SZ - WO_SZ; }
    else                                { s = w2; d = d2;  off = i - WQKV_SZ - WO_SZ - W1_SZ; }
    float4 v = *(const float4*)(s + off);
    ushort4 o;
    o.x = f2bf(v.x); o.y = f2bf(v.y); o.z = f2bf(v.z); o.w = f2bf(v.w);
    *(ushort4*)(d + off) = o;
}

// ---------------------------------------------------------------------------
// 256x256 8-phase NT GEMM (m201-schedule port).
// Split-K partials are written as bf16 at Cb + kpart*slab_stride.
// ---------------------------------------------------------------------------
template<int MU, bool LOADB, bool GATE, typename F>
__device__ __forceinline__
void gphase(f32x4 (&acc)[8][4], bf16x8 (&bfr)[4],
            const unsigned short* slabA, const unsigned short* slabB,
            const int (&aoff)[2][4], const int (&boff)[4], F&& stage, bool gate0)
{
    bf16x8 afr[4];
    if (LOADB) {
        _Pragma("unroll")
        for (int n = 0; n < 4; ++n) bfr[n] = *(const bf16x8*)(slabB + boff[n]);
    }
    _Pragma("unroll")
    for (int m = 0; m < 4; ++m) afr[m] = *(const bf16x8*)(slabA + aoff[MU][m]);
    stage();
    __builtin_amdgcn_s_barrier();
    asm volatile("s_waitcnt lgkmcnt(0)" ::: "memory");
    __builtin_amdgcn_sched_barrier(0);
    __builtin_amdgcn_s_setprio(1);
    _Pragma("unroll")
    for (int m = 0; m < 4; ++m)
        _Pragma("unroll")
        for (int n = 0; n < 4; ++n)
            acc[MU * 4 + m][n] =
                __builtin_amdgcn_mfma_f32_16x16x32_bf16(afr[m], bfr[n], acc[MU * 4 + m][n], 0, 0, 0);
    __builtin_amdgcn_s_setprio(0);
    if (GATE) {
        if (gate0) asm volatile("s_waitcnt vmcnt(0)" ::: "memory");
        else       asm volatile("s_waitcnt vmcnt(4)" ::: "memory");
    }
    __builtin_amdgcn_s_barrier();
}

__global__ __launch_bounds__(512, 2)
void gemm256(const unsigned short* __restrict__ A, const unsigned short* __restrict__ B,
             const float* __restrict__ bias,
             float* __restrict__ Cf, unsigned short* __restrict__ Cb,
             int N, int lda, int klen, int relu, size_t slab_stride)
{
    extern __shared__ unsigned short lds[];   // 131072 B
    auto slA = [&](int buf, int kh) { return lds + (buf * 2 + kh) * 8192; };
    auto slB = [&](int buf, int kh) { return lds + 32768 + (buf * 2 + kh) * 8192; };

    const int nbc = N >> 8;
    const int nwg = gridDim.x;
    const int orig = blockIdx.x;
    const int xcd = orig & 7, lid = orig >> 3;
    const int q = nwg >> 3, r = nwg & 7;
    const int wgid = (xcd < r ? xcd * (q + 1) : r * (q + 1) + (xcd - r) * q) + lid;
    const int brow = wgid / nbc, bcol = wgid % nbc;
    const int kpart = blockIdx.y;

    const int tid = threadIdx.x;
    const int w = tid >> 6, l = tid & 63;
    const int wr = w >> 2, wc = w & 3;
    const int lr = l & 15, lg4 = l >> 4;

    const unsigned short* Ab = A + (size_t)brow * 256 * lda + (size_t)kpart * klen;
    const unsigned short* Bb = B + (size_t)bcol * 256 * lda + (size_t)kpart * klen;
    float* Cfp = Cf;
    unsigned short* Cbp = Cb ? Cb + (size_t)kpart * slab_stride : nullptr;
    const float* biasp = (kpart == 0) ? bias : nullptr;

    const int G0 = w * 128 + l;
    const int tr0 = G0 >> 2;
    const int lg0 = (G0 & 3) ^ ((tr0 >> 1) & 3);

    auto stA = [&](int buf, int kh, int tile) {
        unsigned short* d = slA(buf, kh) + G0 * 8;
        const unsigned short* s = Ab + (size_t)tr0 * lda + tile * 64 + kh * 32 + lg0 * 8;
        gll16(s, d);
        gll16(s + (size_t)16 * lda, d + 512);
    };
    auto stB = [&](int buf, int kh, int tile) {
        unsigned short* d = slB(buf, kh) + G0 * 8;
        const unsigned short* s = Bb + (size_t)tr0 * lda + tile * 64 + kh * 32 + lg0 * 8;
        gll16(s, d);
        gll16(s + (size_t)16 * lda, d + 512);
    };

    int aoff[2][4], boff[4];
    #pragma unroll
    for (int mu = 0; mu < 2; ++mu)
        #pragma unroll
        for (int m = 0; m < 4; ++m) {
            int tA = wr * 128 + mu * 64 + m * 16 + lr;
            aoff[mu][m] = tA * 32 + ((lg4 ^ ((tA >> 1) & 3)) << 3);
        }
    #pragma unroll
    for (int n = 0; n < 4; ++n) {
        int tB = wc * 64 + n * 16 + lr;
        boff[n] = tB * 32 + ((lg4 ^ ((tB >> 1) & 3)) << 3);
    }

    f32x4 acc[8][4] = {};

    const int KT = klen >> 6;
    stA(0, 0, 0); stA(0, 1, 0); stB(0, 0, 0); stB(0, 1, 0);
    if (KT > 1) { stA(1, 0, 1); stA(1, 1, 1); stB(1, 0, 1); stB(1, 1, 1); }
    asm volatile("s_waitcnt vmcnt(0)" ::: "memory");
    __builtin_amdgcn_s_barrier();

    for (int I = 0; I < KT / 2; ++I) {
        const int t2 = 2 * I;
        const bool s12 = (I > 0);
        const bool more = (t2 + 2 < KT);
        bf16x8 bfr[4];
        gphase<0, true , false>(acc, bfr, slA(0,0), slB(0,0), aoff, boff, [&]{ if (s12)  stA(1,1,t2+1); }, false);
        gphase<1, false, false>(acc, bfr, slA(0,0), slB(0,0), aoff, boff, [&]{ if (s12)  stB(1,1,t2+1); }, false);
        gphase<0, true , false>(acc, bfr, slA(0,1), slB(0,1), aoff, boff, [&]{ if (more) stA(0,0,t2+2); }, false);
        gphase<1, false, true >(acc, bfr, slA(0,1), slB(0,1), aoff, boff, [&]{ if (more) stB(0,0,t2+2); }, !more);
        gphase<0, true , false>(acc, bfr, slA(1,0), slB(1,0), aoff, boff, [&]{ if (more) stA(0,1,t2+2); }, false);
        gphase<1, false, false>(acc, bfr, slA(1,0), slB(1,0), aoff, boff, [&]{ if (more) stB(0,1,t2+2); }, false);
        gphase<0, true , false>(acc, bfr, slA(1,1), slB(1,1), aoff, boff, [&]{ if (more) stA(1,0,t2+3); }, false);
        gphase<1, false, true >(acc, bfr, slA(1,1), slB(1,1), aoff, boff, [&]{ if (more) stB(1,0,t2+3); }, !more);
    }

    const int crow0 = brow * 256 + wr * 128;
    const int ccol0 = bcol * 256 + wc * 64;
    #pragma unroll
    for (int n = 0; n < 4; ++n) {
        int col = ccol0 + n * 16 + lr;
        float bv = biasp ? biasp[col] : 0.0f;
        #pragma unroll
        for (int m = 0; m < 8; ++m) {
            int row0 = crow0 + m * 16 + lg4 * 4;
            size_t base_i = (size_t)row0 * N + col;
            #pragma unroll
            for (int j = 0; j < 4; ++j) {
                float v = acc[m][n][j] + bv;
                if (relu) v = fmaxf(v, 0.0f);
                size_t idx = base_i + (size_t)j * N;
                if (Cfp) Cfp[idx] = v;
                if (Cbp) Cbp[idx] = f2bf(v);
            }
        }
    }
}

// ---------------------------------------------------------------------------
// Flash attention, scalar-slope ALiBi. QBLK=64, two k-tiles per iteration,
// T5 setprio, min-3-waves/EU, BAND TRUNCATION over {qt-2..qt+2}
// (error below bf16 ulp — see round-13 analysis).
// ---------------------------------------------------------------------------
__global__ __launch_bounds__(256, 3)
void attn_alibi(const unsigned short* __restrict__ qkv,
                unsigned short* __restrict__ out,
                float slope2)   // slope * log2(e)
{
    const int bid = blockIdx.x;
    const int id = (bid & 7) * 128 + (bid >> 3);   // XCD-chunk: one (b,h) per L2
    const int qt = id & 15;
    const int bh = id >> 4;
    const int h  = bh & (N_HEADS - 1);
    const int b  = bh >> 4;
    const int w  = threadIdx.x >> 6, l = threadIdx.x & 63;
    const int lr = l & 15, lg = l >> 4;

    __shared__ __align__(16) unsigned short lsK[2][64 * 64];
    __shared__ __align__(16) unsigned short lsVt[2][64 * 64];
    __shared__ __align__(16) unsigned short lsP[4 * 16 * 64];

    const size_t rs = 3 * D_MODEL;
    const unsigned short* base = qkv + (size_t)b * SEQ * rs;
    const int qrow_w = qt * 64 + w * 16;
    const float c1 = 0.125f * 1.4426950408889634f;   // scale * log2(e)

    bf16x8 aq[2];
    #pragma unroll
    for (int ks = 0; ks < 2; ++ks)
        aq[ks] = *(const bf16x8*)(base + (size_t)(qrow_w + lr) * rs + h * HEAD_DIM + ks * 32 + lg * 8);

    float m_run = -1e30f, s_run = 0.f;
    f32x4 oacc[4] = {};
    const float qi = (float)(qrow_w + lr);   // this lane's q row (for S^T)

    auto stageK = [&](int buf, int kt) {
        #pragma unroll
        for (int i = 0; i < 2; ++i) {
            int chunk = i * 4 + w;
            int e = chunk * 512 + l * 8;
            int row = e >> 6, c = e & 63;
            int gcol = c ^ ((row & 7) << 3);
            gll16(base + (size_t)(kt * 64 + row) * rs + D_MODEL + h * HEAD_DIM + gcol,
                  &lsK[buf][chunk * 512]);
        }
    };
    auto stageV = [&](int buf, int kt) {
        #pragma unroll
        for (int i = 0; i < 2; ++i) {
            int oct = i * 4 + w;
            int kj  = l;
            u16x8 v = *(const u16x8*)(base + (size_t)(kt * 64 + kj) * rs + 2 * D_MODEL + h * HEAD_DIM + oct * 8);
            #pragma unroll
            for (int jj = 0; jj < 8; ++jj) {
                int row = oct * 8 + jj;
                lsVt[buf][row * 64 + (kj ^ ((row & 7) << 3))] = v[jj];
            }
        }
    };

    // band: pairs p covering k-tiles {qt-2..qt+2} (clamped)
    const int p_lo = max(0, (qt - 2) >> 1);
    const int p_hi = min(SEQ / 128, ((qt + 2) >> 1) + 1);

    for (int p = p_lo; p < p_hi; ++p) {
        const int kt0 = 2 * p;
        stageK(0, kt0); stageK(1, kt0 + 1);
        stageV(0, kt0); stageV(1, kt0 + 1);
        __syncthreads();

        // --- QK^T swapped, both tiles (independent MFMA chains)
        f32x4 s0[4] = {}, s1[4] = {};
        __builtin_amdgcn_s_setprio(1);
        #pragma unroll
        for (int ks = 0; ks < 2; ++ks) {
            #pragma unroll
            for (int n = 0; n < 4; ++n) {
                int row = n * 16 + lr;
                int co = (ks * 32 + lg * 8) ^ ((row & 7) << 3);
                bf16x8 bk0 = *(const bf16x8*)&lsK[0][row * 64 + co];
                bf16x8 bk1 = *(const bf16x8*)&lsK[1][row * 64 + co];
                s0[n] = __builtin_amdgcn_mfma_f32_16x16x32_bf16(bk0, aq[ks], s0[n], 0, 0, 0);
                s1[n] = __builtin_amdgcn_mfma_f32_16x16x32_bf16(bk1, aq[ks], s1[n], 0, 0, 0);
            }
        }
        __builtin_amdgcn_s_setprio(0);

        // --- joint ALiBi + max over both tiles (32 scores/lane)
        float mx = -1e30f;
        #pragma unroll
        for (int n = 0; n < 4; ++n)
            #pragma unroll
            for (int jj = 0; jj < 4; ++jj) {
                float k0f = (float)(kt0 * 64 + n * 16 + lg * 4 + jj);
                float v0 = fmaf(s0[n][jj], c1, -slope2 * fabsf(qi - k0f));
                float v1 = fmaf(s1[n][jj], c1, -slope2 * fabsf(qi - k0f - 64.0f));
                s0[n][jj] = v0;
                s1[n][jj] = v1;
                mx = fmaxf(mx, fmaxf(v0, v1));
            }
        mx = fmaxf(mx, __shfl_xor(mx, 16));
        mx = fmaxf(mx, __shfl_xor(mx, 32));
        if (__any(mx > m_run + 8.0f)) {
            float mnew = fmaxf(m_run, mx);
            float corr = fexp2(m_run - mnew);
            m_run = mnew;
            s_run *= corr;
            #pragma unroll
            for (int j = 0; j < 4; ++j) {
                float cj = __shfl(corr, lg * 4 + j);   // corr g-uniform: lane q=lg*4+j
                #pragma unroll
                for (int nd = 0; nd < 4; ++nd)
                    oacc[nd][j] *= cj;
            }
        }
        // --- exp both tiles, interleaved (independent chains)
        float psum = 0.f;
        #pragma unroll
        for (int n = 0; n < 4; ++n)
            #pragma unroll
            for (int jj = 0; jj < 4; ++jj) {
                float p0 = fexp2(s0[n][jj] - m_run);
                float p1 = fexp2(s1[n][jj] - m_run);
                s0[n][jj] = p0;
                s1[n][jj] = p1;
                psum += p0 + p1;
            }
        psum += __shfl_xor(psum, 16);
        psum += __shfl_xor(psum, 32);
        s_run += psum;

        // --- pack P + PV, tile 0 then tile 1 (wave-local lsP region)
        #pragma unroll
        for (int t = 0; t < 2; ++t) {
            #pragma unroll
            for (int n = 0; n < 4; ++n) {
                f32x4 sv = t ? s1[n] : s0[n];
                bf16x4 pk;
                pk[0] = (__bf16)sv[0]; pk[1] = (__bf16)sv[1];
                pk[2] = (__bf16)sv[2]; pk[3] = (__bf16)sv[3];
                *(bf16x4*)&lsP[w * 1024 + lr * 64 + ((n * 16 + lg * 4) ^ ((lr & 7) << 3))] = pk;
            }
            __builtin_amdgcn_s_setprio(1);
            #pragma unroll
            for (int ks = 0; ks < 2; ++ks) {
                bf16x8 ap = *(const bf16x8*)&lsP[w * 1024 + lr * 64 + ((ks * 32 + lg * 8) ^ ((lr & 7) << 3))];
                #pragma unroll
                for (int nd = 0; nd < 4; ++nd) {
                    int row = nd * 16 + lr;
                    bf16x8 bv = *(const bf16x8*)&lsVt[t][row * 64 + ((ks * 32 + lg * 8) ^ ((row & 7) << 3))];
                    oacc[nd] = __builtin_amdgcn_mfma_f32_16x16x32_bf16(ap, bv, oacc[nd], 0, 0, 0);
                }
            }
            __builtin_amdgcn_s_setprio(0);
        }
        __syncthreads();
    }

    // --- normalize (1/s_run lives at lane q=lr; broadcast to oacc layout)
    float inv = 1.0f / s_run;
    #pragma unroll
    for (int j = 0; j < 4; ++j) {
        float invj = __shfl(inv, lg * 4 + j);
        int qrow = qrow_w + lg * 4 + j;
        #pragma unroll
        for (int nd = 0; nd < 4; ++nd) {
            int d = nd * 16 + lr;
            out[((size_t)b * SEQ + qrow) * D_MODEL + h * HEAD_DIM + d] = f2bf(oacc[nd][j] * invj);
        }
    }
}

// ---------------------------------------------------------------------------
// Wave-level add+LN: 1 row per WAVE (4 rows/block, grid MT/4). Lane owns 16
// elems as two perfect 16B bursts; reduction = 6 shfl_xor, no LDS/barrier.
// ---------------------------------------------------------------------------
__global__ __launch_bounds__(256)
void add_ln(const unsigned short* __restrict__ resid, const unsigned short* __restrict__ delta,
            size_t slab, int nslab,
            const float* __restrict__ g, const float* __restrict__ beta,
            unsigned short* __restrict__ out_b)
{
    const int w = threadIdx.x >> 6, l = threadIdx.x & 63;
    const int row = blockIdx.x * 4 + w;
    const size_t off0 = (size_t)row * D_MODEL + l * 8;

    float x[16];
    #pragma unroll
    for (int c = 0; c < 2; ++c) {
        u16x8 rv = *(const u16x8*)(resid + off0 + c * 512);
        #pragma unroll
        for (int j = 0; j < 8; ++j) x[c * 8 + j] = bf2f(rv[j]);
    }
    for (int p = 0; p < nslab; ++p) {
        #pragma unroll
        for (int c = 0; c < 2; ++c) {
            u16x8 dv = *(const u16x8*)(delta + p * slab + off0 + c * 512);
            #pragma unroll
            for (int j = 0; j < 8; ++j) x[c * 8 + j] += bf2f(dv[j]);
        }
    }
    float s = 0.f, s2 = 0.f;
    #pragma unroll
    for (int i = 0; i < 16; ++i) { s += x[i]; s2 += x[i] * x[i]; }
    #pragma unroll
    for (int d = 1; d < 64; d <<= 1) {
        s  += __shfl_xor(s, d);
        s2 += __shfl_xor(s2, d);
    }
    float mu  = s * (1.0f / D_MODEL);
    float var = s2 * (1.0f / D_MODEL) - mu * mu;
    float rsq = rsqrtf(var + 1e-5f);

    #pragma unroll
    for (int c = 0; c < 2; ++c) {
        int e0 = l * 8 + c * 512;
        float4 g0 = *(const float4*)(g + e0);
        float4 g1 = *(const float4*)(g + e0 + 4);
        float4 b0 = *(const float4*)(beta + e0);
        float4 b1 = *(const float4*)(beta + e0 + 4);
        float gv[8] = {g0.x, g0.y, g0.z, g0.w, g1.x, g1.y, g1.z, g1.w};
        float bv[8] = {b0.x, b0.y, b0.z, b0.w, b1.x, b1.y, b1.z, b1.w};
        u16x8 ov;
        #pragma unroll
        for (int j = 0; j < 8; ++j)
            ov[j] = f2bf((x[c * 8 + j] - mu) * rsq * gv[j] + bv[j]);
        *(u16x8*)(out_b + off0 + c * 512) = ov;
    }
}

// ---------------------------------------------------------------------------
// Head: grid = N_CLS blocks x 256 threads; wave wv handles (b=wv, c=blockIdx).
// ---------------------------------------------------------------------------
__global__ __launch_bounds__(256)
void head_kernel(const unsigned short* __restrict__ h, const float* __restrict__ hw,
                 const float* __restrict__ hb, float* __restrict__ out)
{
    const int wv = threadIdx.x >> 6, l = threadIdx.x & 63;
    const int c = blockIdx.x;
    const unsigned short* hr = h + ((size_t)wv * SEQ + (SEQ - 1)) * D_MODEL;
    const float* wc = hw + (size_t)c * D_MODEL;
    float s = 0.f;
    #pragma unroll
    for (int i = 0; i < 16; ++i) {
        int k = i * 64 + l;
        s += bf2f(hr[k]) * wc[k];
    }
    #pragma unroll
    for (int d = 1; d < 64; d <<= 1)
        s += __shfl_xor(s, d);
    if (l == 0) out[wv * N_CLS + c] = s + hb[c];
}

// ---------------------------------------------------------------------------
extern "C" void kernel_launch(void* const* d_in, const int* in_sizes, int n_in,
                              void* d_out, int out_size, void* d_ws, size_t ws_size,
                              hipStream_t stream)
{
    const float* x     = (const float*)d_in[0];
    const float* in_w  = (const float*)d_in[1];
    const float* in_b  = (const float*)d_in[2];
    const float* Wqkv  = (const float*)d_in[3];
    const float* bqkv  = (const float*)d_in[4];
    const float* Wo    = (const float*)d_in[5];
    const float* bo    = (const float*)d_in[6];
    const float* ln1g  = (const float*)d_in[7];
    const float* ln1b  = (const float*)d_in[8];
    const float* ln2g  = (const float*)d_in[9];
    const float* ln2b  = (const float*)d_in[10];
    const float* W1    = (const float*)d_in[11];
    const float* b1    = (const float*)d_in[12];
    const float* W2    = (const float*)d_in[13];
    const float* b2    = (const float*)d_in[14];
    const float* headw = (const float*)d_in[15];
    const float* headb = (const float*)d_in[16];
    float* out = (float*)d_out;

    (void)hipFuncSetAttribute((const void*)gemm256, hipFuncAttributeMaxDynamicSharedMemorySize, 131072);

    char* ws = (char*)d_ws;
    size_t off = 0;
    auto alloc = [&](size_t bytes) -> void* {
        void* p = ws + off;
        off += (bytes + 255) & ~(size_t)255;
        return p;
    };
    const int MT = BATCH * SEQ;  // 4096
    const size_t SLAB = (size_t)MT * D_MODEL;

    unsigned short* x_bf   = (unsigned short*)alloc((size_t)MT * IN_DIM * 2);
    unsigned short* h_bf   = (unsigned short*)alloc(SLAB * 2);
    unsigned short* qkv_bf = (unsigned short*)alloc((size_t)MT * 3 * D_MODEL * 2);
    unsigned short* att_bf = (unsigned short*)alloc(SLAB * 2);
    unsigned short* ff_bf  = (unsigned short*)alloc((size_t)MT * FF_DIM * 2);
    unsigned short* tmp_bf = (unsigned short*)alloc(SLAB * 2 * 4);   // up to 4 bf16 split-K slabs
    unsigned short* win_bf = (unsigned short*)alloc((size_t)D_MODEL * IN_DIM * 2);
    unsigned short* wq_bf  = (unsigned short*)alloc((size_t)WQKV_SZ * 2);
    unsigned short* wo_bf  = (unsigned short*)alloc((size_t)WO_SZ * 2);
    unsigned short* w1_bf  = (unsigned short*)alloc((size_t)W1_SZ * 2);
    unsigned short* w2_bf  = (unsigned short*)alloc((size_t)W2_SZ * 2);

    double ssum = 0.0;
    for (int i = 1; i <= N_HEADS; ++i) ssum += pow(2.0, -8.0 * i / N_HEADS);
    const float slope = (float)(ssum / N_HEADS);
    const float slope2 = slope * 1.4426950408889634f;

    auto cvt = [&](const float* s, unsigned short* d, int n) {
        cvt_f32_bf16<<<n / 1024, 256, 0, stream>>>(s, d, n);
    };

    // input projection: M=4096, N=1024, K=256 (bf16 output only)
    cvt(x, x_bf, MT * IN_DIM);
    cvt(in_w, win_bf, D_MODEL * IN_DIM);
    gemm256<<<dim3(16 * 4, 1), 512, 131072, stream>>>(
        x_bf, win_bf, in_b, nullptr, h_bf, D_MODEL, IN_DIM, IN_DIM, 0, 0);

    const int CVT_BLKS = (WQKV_SZ + WO_SZ + W1_SZ + W2_SZ) / 1024;   // 12288

    for (int layer = 0; layer < N_LAYERS; ++layer) {
        cvt_layer<<<CVT_BLKS, 256, 0, stream>>>(
            Wqkv + (size_t)layer * WQKV_SZ, Wo + (size_t)layer * WO_SZ,
            W1 + (size_t)layer * W1_SZ, W2 + (size_t)layer * W2_SZ,
            wq_bf, wo_bf, w1_bf, w2_bf);

        // QKV: M=4096, N=3072, K=1024 -> 192 blocks
        gemm256<<<dim3(16 * 12, 1), 512, 131072, stream>>>(
            h_bf, wq_bf, bqkv + (size_t)layer * 3 * D_MODEL,
            nullptr, qkv_bf, 3 * D_MODEL, D_MODEL, D_MODEL, 0, 0);

        attn_alibi<<<BATCH * N_HEADS * (SEQ / 64), 256, 0, stream>>>(qkv_bf, att_bf, slope2);

        // Wo: split-K x2 -> 128 blocks (KT=8 amortizes prologue), bf16 partials
        gemm256<<<dim3(16 * 4, 2), 512, 131072, stream>>>(
            att_bf, wo_bf, bo + (size_t)layer * D_MODEL,
            nullptr, tmp_bf, D_MODEL, D_MODEL, D_MODEL / 2, 0, SLAB);

        add_ln<<<MT / 4, 256, 0, stream>>>(h_bf, tmp_bf, SLAB, 2,
            ln1g + (size_t)layer * D_MODEL, ln1b + (size_t)layer * D_MODEL, h_bf);

        // FF1: M=4096, N=4096, K=1024 -> 256 blocks, ReLU
        gemm256<<<dim3(16 * 16, 1), 512, 131072, stream>>>(
            h_bf, w1_bf, b1 + (size_t)layer * FF_DIM,
            nullptr, ff_bf, FF_DIM, D_MODEL, D_MODEL, 1, 0);

        // FF2: split-K x4 -> 256 blocks, bf16 partials
        gemm256<<<dim3(16 * 4, 4), 512, 131072, stream>>>(
            ff_bf, w2_bf, b2 + (size_t)layer * D_MODEL,
            nullptr, tmp_bf, D_MODEL, FF_DIM, FF_DIM / 4, 0, SLAB);

        add_ln<<<MT / 4, 256, 0, stream>>>(h_bf, tmp_bf, SLAB, 4,
            ln2g + (size_t)layer * D_MODEL, ln2b + (size_t)layer * D_MODEL, h_bf);
    }

    head_kernel<<<N_CLS, 256, 0, stream>>>(h_bf, headw, headb, out);
}

// Round 18
// 1215.450 us; speedup vs baseline: 1.1328x; 1.0154x over previous
//
#include <hip/hip_runtime.h>
#include <cmath>

#define D_MODEL 1024
#define N_HEADS 16
#define HEAD_DIM 64
#define SEQ 1024
#define BATCH 4
#define FF_DIM 4096
#define IN_DIM 256
#define N_LAYERS 6
#define N_CLS 10

typedef __bf16 bf16x8 __attribute__((ext_vector_type(8)));
typedef __bf16 bf16x4 __attribute__((ext_vector_type(4)));
typedef float f32x4 __attribute__((ext_vector_type(4)));
typedef unsigned short u16x8 __attribute__((ext_vector_type(8)));

__device__ __forceinline__ unsigned short f2bf(float f) {
    return __builtin_bit_cast(unsigned short, (__bf16)f);   // RNE; pairs fuse to v_cvt_pk_bf16_f32
}
__device__ __forceinline__ float bf2f(unsigned short u) {
    return __uint_as_float((unsigned int)u << 16);
}
__device__ __forceinline__ float fexp2(float x) {
    return __builtin_amdgcn_exp2f(x);   // v_exp_f32 (base-2 native)
}

__device__ __forceinline__ void gll16(const void* g, void* l) {
    __builtin_amdgcn_global_load_lds((const __attribute__((address_space(1))) void*)g,
                                     (__attribute__((address_space(3))) void*)l, 16, 0, 0);
}

// ---------------------------------------------------------------------------
// f32 -> bf16 convert: 8 elems/thread (2x float4 in flight -> BW floor).
// ---------------------------------------------------------------------------
__device__ __forceinline__ void cvt8(const float* __restrict__ s, unsigned short* __restrict__ d) {
    float4 v0 = *(const float4*)s;
    float4 v1 = *(const float4*)(s + 4);
    u16x8 o;
    o[0] = f2bf(v0.x); o[1] = f2bf(v0.y); o[2] = f2bf(v0.z); o[3] = f2bf(v0.w);
    o[4] = f2bf(v1.x); o[5] = f2bf(v1.y); o[6] = f2bf(v1.z); o[7] = f2bf(v1.w);
    *(u16x8*)d = o;
}

__global__ __launch_bounds__(256)
void cvt_f32_bf16(const float* __restrict__ src, unsigned short* __restrict__ dst, int n) {
    int i = (blockIdx.x * 256 + threadIdx.x) * 8;
    if (i + 8 <= n) cvt8(src + i, dst + i);
}

// ---------------------------------------------------------------------------
// One-shot per-layer weight convert: Wqkv | Wo | W1 | W2 in a single launch.
// 8 elems/thread; all section sizes divisible by 8 so each thread stays in
// one region. (Round-16 lesson: this bf16 pre-pass HALVES the GEMM working
// set — keeping it beats staging f32 weights directly.)
// ---------------------------------------------------------------------------
#define WQKV_SZ (3 * D_MODEL * D_MODEL)
#define WO_SZ   (D_MODEL * D_MODEL)
#define W1_SZ   (FF_DIM * D_MODEL)
#define W2_SZ   (D_MODEL * FF_DIM)
__global__ __launch_bounds__(256)
void cvt_layer(const float* __restrict__ wq, const float* __restrict__ wo,
               const float* __restrict__ w1, const float* __restrict__ w2,
               unsigned short* __restrict__ dq, unsigned short* __restrict__ dvo,
               unsigned short* __restrict__ d1, unsigned short* __restrict__ d2)
{
    int i = (blockIdx.x * 256 + threadIdx.x) * 8;
    const float* s; unsigned short* d; int off;
    if (i < WQKV_SZ)                      { s = wq; d = dq;  off = i; }
    else if (i < WQKV_SZ + WO_SZ)         { s = wo; d = dvo; off = i - WQKV_SZ; }
    else if (i < WQKV_SZ + WO_SZ + W1_SZ) { s = w1; d = d1;  off = i - WQKV_SZ - WO_SZ; }
    else                                  { s = w2; d = d2;  off = i - WQKV_SZ - WO_SZ - W1_SZ; }
    cvt8(s + off, d + off);
}

// ---------------------------------------------------------------------------
// 256x256 8-phase NT GEMM (m201-schedule port).
// Split-K partials are written as bf16 at Cb + kpart*slab_stride.
// ---------------------------------------------------------------------------
template<int MU, bool LOADB, bool GATE, typename F>
__device__ __forceinline__
void gphase(f32x4 (&acc)[8][4], bf16x8 (&bfr)[4],
            const unsigned short* slabA, const unsigned short* slabB,
            const int (&aoff)[2][4], const int (&boff)[4], F&& stage, bool gate0)
{
    bf16x8 afr[4];
    if (LOADB) {
        _Pragma("unroll")
        for (int n = 0; n < 4; ++n) bfr[n] = *(const bf16x8*)(slabB + boff[n]);
    }
    _Pragma("unroll")
    for (int m = 0; m < 4; ++m) afr[m] = *(const bf16x8*)(slabA + aoff[MU][m]);
    stage();
    __builtin_amdgcn_s_barrier();
    asm volatile("s_waitcnt lgkmcnt(0)" ::: "memory");
    __builtin_amdgcn_sched_barrier(0);
    __builtin_amdgcn_s_setprio(1);
    _Pragma("unroll")
    for (int m = 0; m < 4; ++m)
        _Pragma("unroll")
        for (int n = 0; n < 4; ++n)
            acc[MU * 4 + m][n] =
                __builtin_amdgcn_mfma_f32_16x16x32_bf16(afr[m], bfr[n], acc[MU * 4 + m][n], 0, 0, 0);
    __builtin_amdgcn_s_setprio(0);
    if (GATE) {
        if (gate0) asm volatile("s_waitcnt vmcnt(0)" ::: "memory");
        else       asm volatile("s_waitcnt vmcnt(4)" ::: "memory");
    }
    __builtin_amdgcn_s_barrier();
}

__global__ __launch_bounds__(512, 2)
void gemm256(const unsigned short* __restrict__ A, const unsigned short* __restrict__ B,
             const float* __restrict__ bias,
             float* __restrict__ Cf, unsigned short* __restrict__ Cb,
             int N, int lda, int klen, int relu, size_t slab_stride)
{
    extern __shared__ unsigned short lds[];   // 131072 B
    auto slA = [&](int buf, int kh) { return lds + (buf * 2 + kh) * 8192; };
    auto slB = [&](int buf, int kh) { return lds + 32768 + (buf * 2 + kh) * 8192; };

    const int nbc = N >> 8;
    const int nwg = gridDim.x;
    const int orig = blockIdx.x;
    const int xcd = orig & 7, lid = orig >> 3;
    const int q = nwg >> 3, r = nwg & 7;
    const int wgid = (xcd < r ? xcd * (q + 1) : r * (q + 1) + (xcd - r) * q) + lid;
    const int brow = wgid / nbc, bcol = wgid % nbc;
    const int kpart = blockIdx.y;

    const int tid = threadIdx.x;
    const int w = tid >> 6, l = tid & 63;
    const int wr = w >> 2, wc = w & 3;
    const int lr = l & 15, lg4 = l >> 4;

    const unsigned short* Ab = A + (size_t)brow * 256 * lda + (size_t)kpart * klen;
    const unsigned short* Bb = B + (size_t)bcol * 256 * lda + (size_t)kpart * klen;
    float* Cfp = Cf;
    unsigned short* Cbp = Cb ? Cb + (size_t)kpart * slab_stride : nullptr;
    const float* biasp = (kpart == 0) ? bias : nullptr;

    const int G0 = w * 128 + l;
    const int tr0 = G0 >> 2;
    const int lg0 = (G0 & 3) ^ ((tr0 >> 1) & 3);

    auto stA = [&](int buf, int kh, int tile) {
        unsigned short* d = slA(buf, kh) + G0 * 8;
        const unsigned short* s = Ab + (size_t)tr0 * lda + tile * 64 + kh * 32 + lg0 * 8;
        gll16(s, d);
        gll16(s + (size_t)16 * lda, d + 512);
    };
    auto stB = [&](int buf, int kh, int tile) {
        unsigned short* d = slB(buf, kh) + G0 * 8;
        const unsigned short* s = Bb + (size_t)tr0 * lda + tile * 64 + kh * 32 + lg0 * 8;
        gll16(s, d);
        gll16(s + (size_t)16 * lda, d + 512);
    };

    int aoff[2][4], boff[4];
    #pragma unroll
    for (int mu = 0; mu < 2; ++mu)
        #pragma unroll
        for (int m = 0; m < 4; ++m) {
            int tA = wr * 128 + mu * 64 + m * 16 + lr;
            aoff[mu][m] = tA * 32 + ((lg4 ^ ((tA >> 1) & 3)) << 3);
        }
    #pragma unroll
    for (int n = 0; n < 4; ++n) {
        int tB = wc * 64 + n * 16 + lr;
        boff[n] = tB * 32 + ((lg4 ^ ((tB >> 1) & 3)) << 3);
    }

    f32x4 acc[8][4] = {};

    const int KT = klen >> 6;
    stA(0, 0, 0); stA(0, 1, 0); stB(0, 0, 0); stB(0, 1, 0);
    if (KT > 1) { stA(1, 0, 1); stA(1, 1, 1); stB(1, 0, 1); stB(1, 1, 1); }
    asm volatile("s_waitcnt vmcnt(0)" ::: "memory");
    __builtin_amdgcn_s_barrier();

    for (int I = 0; I < KT / 2; ++I) {
        const int t2 = 2 * I;
        const bool s12 = (I > 0);
        const bool more = (t2 + 2 < KT);
        bf16x8 bfr[4];
        gphase<0, true , false>(acc, bfr, slA(0,0), slB(0,0), aoff, boff, [&]{ if (s12)  stA(1,1,t2+1); }, false);
        gphase<1, false, false>(acc, bfr, slA(0,0), slB(0,0), aoff, boff, [&]{ if (s12)  stB(1,1,t2+1); }, false);
        gphase<0, true , false>(acc, bfr, slA(0,1), slB(0,1), aoff, boff, [&]{ if (more) stA(0,0,t2+2); }, false);
        gphase<1, false, true >(acc, bfr, slA(0,1), slB(0,1), aoff, boff, [&]{ if (more) stB(0,0,t2+2); }, !more);
        gphase<0, true , false>(acc, bfr, slA(1,0), slB(1,0), aoff, boff, [&]{ if (more) stA(0,1,t2+2); }, false);
        gphase<1, false, false>(acc, bfr, slA(1,0), slB(1,0), aoff, boff, [&]{ if (more) stB(0,1,t2+2); }, false);
        gphase<0, true , false>(acc, bfr, slA(1,1), slB(1,1), aoff, boff, [&]{ if (more) stA(1,0,t2+3); }, false);
        gphase<1, false, true >(acc, bfr, slA(1,1), slB(1,1), aoff, boff, [&]{ if (more) stB(1,0,t2+3); }, !more);
    }

    const int crow0 = brow * 256 + wr * 128;
    const int ccol0 = bcol * 256 + wc * 64;
    #pragma unroll
    for (int n = 0; n < 4; ++n) {
        int col = ccol0 + n * 16 + lr;
        float bv = biasp ? biasp[col] : 0.0f;
        #pragma unroll
        for (int m = 0; m < 8; ++m) {
            int row0 = crow0 + m * 16 + lg4 * 4;
            size_t base_i = (size_t)row0 * N + col;
            #pragma unroll
            for (int j = 0; j < 4; ++j) {
                float v = acc[m][n][j] + bv;
                if (relu) v = fmaxf(v, 0.0f);
                size_t idx = base_i + (size_t)j * N;
                if (Cfp) Cfp[idx] = v;
                if (Cbp) Cbp[idx] = f2bf(v);
            }
        }
    }
}

// ---------------------------------------------------------------------------
// Flash attention, scalar-slope ALiBi. QBLK=64, two k-tiles per iteration,
// T5 setprio, min-3-waves/EU, BAND TRUNCATION over {qt-2..qt+2}
// (error below bf16 ulp — see round-13 analysis).
// ---------------------------------------------------------------------------
__global__ __launch_bounds__(256, 3)
void attn_alibi(const unsigned short* __restrict__ qkv,
                unsigned short* __restrict__ out,
                float slope2)   // slope * log2(e)
{
    const int bid = blockIdx.x;
    const int id = (bid & 7) * 128 + (bid >> 3);   // XCD-chunk: one (b,h) per L2
    const int qt = id & 15;
    const int bh = id >> 4;
    const int h  = bh & (N_HEADS - 1);
    const int b  = bh >> 4;
    const int w  = threadIdx.x >> 6, l = threadIdx.x & 63;
    const int lr = l & 15, lg = l >> 4;

    __shared__ __align__(16) unsigned short lsK[2][64 * 64];
    __shared__ __align__(16) unsigned short lsVt[2][64 * 64];
    __shared__ __align__(16) unsigned short lsP[4 * 16 * 64];

    const size_t rs = 3 * D_MODEL;
    const unsigned short* base = qkv + (size_t)b * SEQ * rs;
    const int qrow_w = qt * 64 + w * 16;
    const float c1 = 0.125f * 1.4426950408889634f;   // scale * log2(e)

    bf16x8 aq[2];
    #pragma unroll
    for (int ks = 0; ks < 2; ++ks)
        aq[ks] = *(const bf16x8*)(base + (size_t)(qrow_w + lr) * rs + h * HEAD_DIM + ks * 32 + lg * 8);

    float m_run = -1e30f, s_run = 0.f;
    f32x4 oacc[4] = {};
    const float qi = (float)(qrow_w + lr);   // this lane's q row (for S^T)

    auto stageK = [&](int buf, int kt) {
        #pragma unroll
        for (int i = 0; i < 2; ++i) {
            int chunk = i * 4 + w;
            int e = chunk * 512 + l * 8;
            int row = e >> 6, c = e & 63;
            int gcol = c ^ ((row & 7) << 3);
            gll16(base + (size_t)(kt * 64 + row) * rs + D_MODEL + h * HEAD_DIM + gcol,
                  &lsK[buf][chunk * 512]);
        }
    };
    auto stageV = [&](int buf, int kt) {
        #pragma unroll
        for (int i = 0; i < 2; ++i) {
            int oct = i * 4 + w;
            int kj  = l;
            u16x8 v = *(const u16x8*)(base + (size_t)(kt * 64 + kj) * rs + 2 * D_MODEL + h * HEAD_DIM + oct * 8);
            #pragma unroll
            for (int jj = 0; jj < 8; ++jj) {
                int row = oct * 8 + jj;
                lsVt[buf][row * 64 + (kj ^ ((row & 7) << 3))] = v[jj];
            }
        }
    };

    // band: pairs p covering k-tiles {qt-2..qt+2} (clamped)
    const int p_lo = max(0, (qt - 2) >> 1);
    const int p_hi = min(SEQ / 128, ((qt + 2) >> 1) + 1);

    for (int p = p_lo; p < p_hi; ++p) {
        const int kt0 = 2 * p;
        stageK(0, kt0); stageK(1, kt0 + 1);
        stageV(0, kt0); stageV(1, kt0 + 1);
        __syncthreads();

        // --- QK^T swapped, both tiles (independent MFMA chains)
        f32x4 s0[4] = {}, s1[4] = {};
        __builtin_amdgcn_s_setprio(1);
        #pragma unroll
        for (int ks = 0; ks < 2; ++ks) {
            #pragma unroll
            for (int n = 0; n < 4; ++n) {
                int row = n * 16 + lr;
                int co = (ks * 32 + lg * 8) ^ ((row & 7) << 3);
                bf16x8 bk0 = *(const bf16x8*)&lsK[0][row * 64 + co];
                bf16x8 bk1 = *(const bf16x8*)&lsK[1][row * 64 + co];
                s0[n] = __builtin_amdgcn_mfma_f32_16x16x32_bf16(bk0, aq[ks], s0[n], 0, 0, 0);
                s1[n] = __builtin_amdgcn_mfma_f32_16x16x32_bf16(bk1, aq[ks], s1[n], 0, 0, 0);
            }
        }
        __builtin_amdgcn_s_setprio(0);

        // --- joint ALiBi + max over both tiles (32 scores/lane)
        float mx = -1e30f;
        #pragma unroll
        for (int n = 0; n < 4; ++n)
            #pragma unroll
            for (int jj = 0; jj < 4; ++jj) {
                float k0f = (float)(kt0 * 64 + n * 16 + lg * 4 + jj);
                float v0 = fmaf(s0[n][jj], c1, -slope2 * fabsf(qi - k0f));
                float v1 = fmaf(s1[n][jj], c1, -slope2 * fabsf(qi - k0f - 64.0f));
                s0[n][jj] = v0;
                s1[n][jj] = v1;
                mx = fmaxf(mx, fmaxf(v0, v1));
            }
        mx = fmaxf(mx, __shfl_xor(mx, 16));
        mx = fmaxf(mx, __shfl_xor(mx, 32));
        if (__any(mx > m_run + 8.0f)) {
            float mnew = fmaxf(m_run, mx);
            float corr = fexp2(m_run - mnew);
            m_run = mnew;
            s_run *= corr;
            #pragma unroll
            for (int j = 0; j < 4; ++j) {
                float cj = __shfl(corr, lg * 4 + j);   // corr g-uniform: lane q=lg*4+j
                #pragma unroll
                for (int nd = 0; nd < 4; ++nd)
                    oacc[nd][j] *= cj;
            }
        }
        // --- exp both tiles, interleaved (independent chains)
        float psum = 0.f;
        #pragma unroll
        for (int n = 0; n < 4; ++n)
            #pragma unroll
            for (int jj = 0; jj < 4; ++jj) {
                float p0 = fexp2(s0[n][jj] - m_run);
                float p1 = fexp2(s1[n][jj] - m_run);
                s0[n][jj] = p0;
                s1[n][jj] = p1;
                psum += p0 + p1;
            }
        psum += __shfl_xor(psum, 16);
        psum += __shfl_xor(psum, 32);
        s_run += psum;

        // --- pack P + PV, tile 0 then tile 1 (wave-local lsP region)
        #pragma unroll
        for (int t = 0; t < 2; ++t) {
            #pragma unroll
            for (int n = 0; n < 4; ++n) {
                f32x4 sv = t ? s1[n] : s0[n];
                bf16x4 pk;
                pk[0] = (__bf16)sv[0]; pk[1] = (__bf16)sv[1];
                pk[2] = (__bf16)sv[2]; pk[3] = (__bf16)sv[3];
                *(bf16x4*)&lsP[w * 1024 + lr * 64 + ((n * 16 + lg * 4) ^ ((lr & 7) << 3))] = pk;
            }
            __builtin_amdgcn_s_setprio(1);
            #pragma unroll
            for (int ks = 0; ks < 2; ++ks) {
                bf16x8 ap = *(const bf16x8*)&lsP[w * 1024 + lr * 64 + ((ks * 32 + lg * 8) ^ ((lr & 7) << 3))];
                #pragma unroll
                for (int nd = 0; nd < 4; ++nd) {
                    int row = nd * 16 + lr;
                    bf16x8 bv = *(const bf16x8*)&lsVt[t][row * 64 + ((ks * 32 + lg * 8) ^ ((row & 7) << 3))];
                    oacc[nd] = __builtin_amdgcn_mfma_f32_16x16x32_bf16(ap, bv, oacc[nd], 0, 0, 0);
                }
            }
            __builtin_amdgcn_s_setprio(0);
        }
        __syncthreads();
    }

    // --- normalize (1/s_run lives at lane q=lr; broadcast to oacc layout)
    float inv = 1.0f / s_run;
    #pragma unroll
    for (int j = 0; j < 4; ++j) {
        float invj = __shfl(inv, lg * 4 + j);
        int qrow = qrow_w + lg * 4 + j;
        #pragma unroll
        for (int nd = 0; nd < 4; ++nd) {
            int d = nd * 16 + lr;
            out[((size_t)b * SEQ + qrow) * D_MODEL + h * HEAD_DIM + d] = f2bf(oacc[nd][j] * invj);
        }
    }
}

// ---------------------------------------------------------------------------
// Wave-level add+LN: 1 row per WAVE (4 rows/block, grid MT/4). Lane owns 16
// elems as two perfect 16B bursts; reduction = 6 shfl_xor, no LDS/barrier.
// ---------------------------------------------------------------------------
__global__ __launch_bounds__(256)
void add_ln(const unsigned short* __restrict__ resid, const unsigned short* __restrict__ delta,
            size_t slab, int nslab,
            const float* __restrict__ g, const float* __restrict__ beta,
            unsigned short* __restrict__ out_b)
{
    const int w = threadIdx.x >> 6, l = threadIdx.x & 63;
    const int row = blockIdx.x * 4 + w;
    const size_t off0 = (size_t)row * D_MODEL + l * 8;

    float x[16];
    #pragma unroll
    for (int c = 0; c < 2; ++c) {
        u16x8 rv = *(const u16x8*)(resid + off0 + c * 512);
        #pragma unroll
        for (int j = 0; j < 8; ++j) x[c * 8 + j] = bf2f(rv[j]);
    }
    for (int p = 0; p < nslab; ++p) {
        #pragma unroll
        for (int c = 0; c < 2; ++c) {
            u16x8 dv = *(const u16x8*)(delta + p * slab + off0 + c * 512);
            #pragma unroll
            for (int j = 0; j < 8; ++j) x[c * 8 + j] += bf2f(dv[j]);
        }
    }
    float s = 0.f, s2 = 0.f;
    #pragma unroll
    for (int i = 0; i < 16; ++i) { s += x[i]; s2 += x[i] * x[i]; }
    #pragma unroll
    for (int d = 1; d < 64; d <<= 1) {
        s  += __shfl_xor(s, d);
        s2 += __shfl_xor(s2, d);
    }
    float mu  = s * (1.0f / D_MODEL);
    float var = s2 * (1.0f / D_MODEL) - mu * mu;
    float rsq = rsqrtf(var + 1e-5f);

    #pragma unroll
    for (int c = 0; c < 2; ++c) {
        int e0 = l * 8 + c * 512;
        float4 g0 = *(const float4*)(g + e0);
        float4 g1 = *(const float4*)(g + e0 + 4);
        float4 b0 = *(const float4*)(beta + e0);
        float4 b1 = *(const float4*)(beta + e0 + 4);
        float gv[8] = {g0.x, g0.y, g0.z, g0.w, g1.x, g1.y, g1.z, g1.w};
        float bv[8] = {b0.x, b0.y, b0.z, b0.w, b1.x, b1.y, b1.z, b1.w};
        u16x8 ov;
        #pragma unroll
        for (int j = 0; j < 8; ++j)
            ov[j] = f2bf((x[c * 8 + j] - mu) * rsq * gv[j] + bv[j]);
        *(u16x8*)(out_b + off0 + c * 512) = ov;
    }
}

// ---------------------------------------------------------------------------
// Head: grid = N_CLS blocks x 256 threads; wave wv handles (b=wv, c=blockIdx).
// ---------------------------------------------------------------------------
__global__ __launch_bounds__(256)
void head_kernel(const unsigned short* __restrict__ h, const float* __restrict__ hw,
                 const float* __restrict__ hb, float* __restrict__ out)
{
    const int wv = threadIdx.x >> 6, l = threadIdx.x & 63;
    const int c = blockIdx.x;
    const unsigned short* hr = h + ((size_t)wv * SEQ + (SEQ - 1)) * D_MODEL;
    const float* wc = hw + (size_t)c * D_MODEL;
    float s = 0.f;
    #pragma unroll
    for (int i = 0; i < 16; ++i) {
        int k = i * 64 + l;
        s += bf2f(hr[k]) * wc[k];
    }
    #pragma unroll
    for (int d = 1; d < 64; d <<= 1)
        s += __shfl_xor(s, d);
    if (l == 0) out[wv * N_CLS + c] = s + hb[c];
}

// ---------------------------------------------------------------------------
extern "C" void kernel_launch(void* const* d_in, const int* in_sizes, int n_in,
                              void* d_out, int out_size, void* d_ws, size_t ws_size,
                              hipStream_t stream)
{
    const float* x     = (const float*)d_in[0];
    const float* in_w  = (const float*)d_in[1];
    const float* in_b  = (const float*)d_in[2];
    const float* Wqkv  = (const float*)d_in[3];
    const float* bqkv  = (const float*)d_in[4];
    const float* Wo    = (const float*)d_in[5];
    const float* bo    = (const float*)d_in[6];
    const float* ln1g  = (const float*)d_in[7];
    const float* ln1b  = (const float*)d_in[8];
    const float* ln2g  = (const float*)d_in[9];
    const float* ln2b  = (const float*)d_in[10];
    const float* W1    = (const float*)d_in[11];
    const float* b1    = (const float*)d_in[12];
    const float* W2    = (const float*)d_in[13];
    const float* b2    = (const float*)d_in[14];
    const float* headw = (const float*)d_in[15];
    const float* headb = (const float*)d_in[16];
    float* out = (float*)d_out;

    (void)hipFuncSetAttribute((const void*)gemm256, hipFuncAttributeMaxDynamicSharedMemorySize, 131072);

    char* ws = (char*)d_ws;
    size_t off = 0;
    auto alloc = [&](size_t bytes) -> void* {
        void* p = ws + off;
        off += (bytes + 255) & ~(size_t)255;
        return p;
    };
    const int MT = BATCH * SEQ;  // 4096
    const size_t SLAB = (size_t)MT * D_MODEL;

    unsigned short* x_bf   = (unsigned short*)alloc((size_t)MT * IN_DIM * 2);
    unsigned short* h_bf   = (unsigned short*)alloc(SLAB * 2);
    unsigned short* qkv_bf = (unsigned short*)alloc((size_t)MT * 3 * D_MODEL * 2);
    unsigned short* att_bf = (unsigned short*)alloc(SLAB * 2);
    unsigned short* ff_bf  = (unsigned short*)alloc((size_t)MT * FF_DIM * 2);
    unsigned short* tmp_bf = (unsigned short*)alloc(SLAB * 2 * 4);   // up to 4 bf16 split-K slabs
    unsigned short* win_bf = (unsigned short*)alloc((size_t)D_MODEL * IN_DIM * 2);
    unsigned short* wq_bf  = (unsigned short*)alloc((size_t)WQKV_SZ * 2);
    unsigned short* wo_bf  = (unsigned short*)alloc((size_t)WO_SZ * 2);
    unsigned short* w1_bf  = (unsigned short*)alloc((size_t)W1_SZ * 2);
    unsigned short* w2_bf  = (unsigned short*)alloc((size_t)W2_SZ * 2);

    double ssum = 0.0;
    for (int i = 1; i <= N_HEADS; ++i) ssum += pow(2.0, -8.0 * i / N_HEADS);
    const float slope = (float)(ssum / N_HEADS);
    const float slope2 = slope * 1.4426950408889634f;

    auto cvt = [&](const float* s, unsigned short* d, int n) {
        cvt_f32_bf16<<<n / 2048, 256, 0, stream>>>(s, d, n);
    };

    // input projection: M=4096, N=1024, K=256 (bf16 output only)
    cvt(x, x_bf, MT * IN_DIM);
    cvt(in_w, win_bf, D_MODEL * IN_DIM);
    gemm256<<<dim3(16 * 4, 1), 512, 131072, stream>>>(
        x_bf, win_bf, in_b, nullptr, h_bf, D_MODEL, IN_DIM, IN_DIM, 0, 0);

    const int CVT_BLKS = (WQKV_SZ + WO_SZ + W1_SZ + W2_SZ) / 2048;   // 6144

    for (int layer = 0; layer < N_LAYERS; ++layer) {
        cvt_layer<<<CVT_BLKS, 256, 0, stream>>>(
            Wqkv + (size_t)layer * WQKV_SZ, Wo + (size_t)layer * WO_SZ,
            W1 + (size_t)layer * W1_SZ, W2 + (size_t)layer * W2_SZ,
            wq_bf, wo_bf, w1_bf, w2_bf);

        // QKV: M=4096, N=3072, K=1024 -> 192 blocks
        gemm256<<<dim3(16 * 12, 1), 512, 131072, stream>>>(
            h_bf, wq_bf, bqkv + (size_t)layer * 3 * D_MODEL,
            nullptr, qkv_bf, 3 * D_MODEL, D_MODEL, D_MODEL, 0, 0);

        attn_alibi<<<BATCH * N_HEADS * (SEQ / 64), 256, 0, stream>>>(qkv_bf, att_bf, slope2);

        // Wo: split-K x2 -> 128 blocks (KT=8 amortizes prologue), bf16 partials
        gemm256<<<dim3(16 * 4, 2), 512, 131072, stream>>>(
            att_bf, wo_bf, bo + (size_t)layer * D_MODEL,
            nullptr, tmp_bf, D_MODEL, D_MODEL, D_MODEL / 2, 0, SLAB);

        add_ln<<<MT / 4, 256, 0, stream>>>(h_bf, tmp_bf, SLAB, 2,
            ln1g + (size_t)layer * D_MODEL, ln1b + (size_t)layer * D_MODEL, h_bf);

        // FF1: M=4096, N=4096, K=1024 -> 256 blocks, ReLU
        gemm256<<<dim3(16 * 16, 1), 512, 131072, stream>>>(
            h_bf, w1_bf, b1 + (size_t)layer * FF_DIM,
            nullptr, ff_bf, FF_DIM, D_MODEL, D_MODEL, 1, 0);

        // FF2: split-K x4 -> 256 blocks, bf16 partials
        gemm256<<<dim3(16 * 4, 4), 512, 131072, stream>>>(
            ff_bf, w2_bf, b2 + (size_t)layer * D_MODEL,
            nullptr, tmp_bf, D_MODEL, FF_DIM, FF_DIM / 4, 0, SLAB);

        add_ln<<<MT / 4, 256, 0, stream>>>(h_bf, tmp_bf, SLAB, 4,
            ln2g + (size_t)layer * D_MODEL, ln2b + (size_t)layer * D_MODEL, h_bf);
    }

    head_kernel<<<N_CLS, 256, 0, stream>>>(h_bf, headw, headb, out);
}